// Round 2
// baseline (18304.251 us; speedup 1.0000x reference)
//
#include <hip/hip_runtime.h>
#include <math.h>

#define B 1024
#define H 512
#define E 256
#define L 128
#define LE (L*E)   // 32768

// Persistent per-call state lives in module device globals (NOT d_ws):
// round-0 failure signature matched an out-of-bounds d_ws write corrupting
// d_in between graph replays. These are rewritten by init_kernel every call.
__device__ __align__(16) float g_h[2][B*H];
__device__ __align__(16) float g_c[B*H];

__device__ __forceinline__ float sigm(float x) { return 1.0f / (1.0f + expf(-x)); }

// ---------------------------------------------------------------------------
// init: h[0] <- hidden_specs, h[1] <- 0, c <- 0, out[:,0,:] <- one-hot(0)
// ---------------------------------------------------------------------------
__global__ __launch_bounds__(256) void init_kernel(
    const float* __restrict__ hidden, float* __restrict__ out)
{
    int i = blockIdx.x * 256 + threadIdx.x;
    if (i < B*H) { g_h[0][i] = hidden[i]; g_h[1][i] = 0.0f; g_c[i] = 0.0f; }
    if (i < B*E) {
        int b = i >> 8, e = i & 255;
        out[b*LE + e] = (e == 0) ? 1.0f : 0.0f;
    }
}

// ---------------------------------------------------------------------------
// gates: gates = x@W_ih^T + h@W_hh^T + (b_ih+b_hh); LSTM cell update.
// Tile: 64 b-rows x 32 j-cols (x 4 gates). K = 768 (x:256 | h:512), KC=32.
// 512 threads (8 waves -> 2 waves/SIMD): j = tid&31, bg = tid>>5 (16 groups
// of 4 b-rows). LDS float4 rows swizzled kq ^ (row&7) (bank-conflict-free).
// ---------------------------------------------------------------------------
__global__ __launch_bounds__(512) void gates_kernel(
    const float* __restrict__ padded, int t,
    const float* __restrict__ W_ih,  // (2048,256)
    const float* __restrict__ W_hh,  // (2048,512)
    const float* __restrict__ b_ih,
    const float* __restrict__ b_hh)
{
    __shared__ float4 Wl[128][8];   // 16 KB  [row][kq^(row&7)]
    __shared__ float4 XHl[64][8];   //  8 KB  [b][kq^(b&7)]
    const int tid = threadIdx.x;
    const int bbase = blockIdx.x * 64;
    const int jbase = blockIdx.y * 32;
    const int j  = tid & 31;
    const int bg = tid >> 5;                 // 0..15
    const float* __restrict__ h_in  = g_h[t & 1];
    float* __restrict__       h_out = g_h[(t & 1) ^ 1];
    const float* __restrict__ x = padded + (size_t)t * E;

    float acc[4][4];
    #pragma unroll
    for (int bi = 0; bi < 4; ++bi)
        #pragma unroll
        for (int g = 0; g < 4; ++g) acc[bi][g] = 0.0f;

    for (int ck = 0; ck < 24; ++ck) {
        const int k0 = ck * 32;
        const bool isx = (k0 < 256);
        // stage W: 128 rows x 8 quads = 1024 slots, 2/thread
        #pragma unroll
        for (int it = 0; it < 2; ++it) {
            int s = tid + it*512;
            int r = s >> 3, kq = s & 7;
            int g = r >> 5, jj = r & 31;
            int grow = g*512 + jbase + jj;
            const float* src = isx ? (W_ih + grow*256 + k0)
                                   : (W_hh + grow*512 + (k0-256));
            Wl[r][kq ^ (r & 7)] = *(const float4*)(src + kq*4);
        }
        // stage XH: 64 rows x 8 quads = 512 slots, 1/thread
        {
            int b = tid >> 3, kq = tid & 7;
            int gb = bbase + b;
            const float* src = isx ? (x + (size_t)gb*LE + k0)
                                   : (h_in + gb*H + (k0-256));
            XHl[b][kq ^ (b & 7)] = *(const float4*)(src + kq*4);
        }
        __syncthreads();
        #pragma unroll
        for (int kq = 0; kq < 8; ++kq) {
            float4 w0 = Wl[j      ][kq ^ (j & 7)];
            float4 w1 = Wl[32 + j ][kq ^ (j & 7)];
            float4 w2 = Wl[64 + j ][kq ^ (j & 7)];
            float4 w3 = Wl[96 + j ][kq ^ (j & 7)];
            #pragma unroll
            for (int bi = 0; bi < 4; ++bi) {
                int br = bg*4 + bi;
                float4 xv = XHl[br][kq ^ (br & 7)];
                acc[bi][0] += xv.x*w0.x + xv.y*w0.y + xv.z*w0.z + xv.w*w0.w;
                acc[bi][1] += xv.x*w1.x + xv.y*w1.y + xv.z*w1.z + xv.w*w1.w;
                acc[bi][2] += xv.x*w2.x + xv.y*w2.y + xv.z*w2.z + xv.w*w2.w;
                acc[bi][3] += xv.x*w3.x + xv.y*w3.y + xv.z*w3.z + xv.w*w3.w;
            }
        }
        __syncthreads();
    }

    const int jglob = jbase + j;
    const float bs0 = b_ih[jglob]        + b_hh[jglob];
    const float bs1 = b_ih[512 + jglob]  + b_hh[512 + jglob];
    const float bs2 = b_ih[1024 + jglob] + b_hh[1024 + jglob];
    const float bs3 = b_ih[1536 + jglob] + b_hh[1536 + jglob];
    #pragma unroll
    for (int bi = 0; bi < 4; ++bi) {
        int gb = bbase + bg*4 + bi;
        float iv = sigm(acc[bi][0] + bs0);
        float fv = sigm(acc[bi][1] + bs1);
        float gv = tanhf(acc[bi][2] + bs2);
        float ov = sigm(acc[bi][3] + bs3);
        float cv = fv * g_c[gb*H + jglob] + iv * gv;
        g_c[gb*H + jglob] = cv;
        h_out[gb*H + jglob] = ov * tanhf(cv);
    }
}

// ---------------------------------------------------------------------------
// mlp: tok = W3@relu(W2@relu(W1@h+b1)+b2)+b3 for 4 batch rows per block.
// z1/z2 live in LDS only. Weights read from global (L2-resident).
// ---------------------------------------------------------------------------
__global__ __launch_bounds__(256) void mlp_kernel(
    int sel,
    const float* __restrict__ W1, const float* __restrict__ b1,
    const float* __restrict__ W2, const float* __restrict__ b2,
    const float* __restrict__ W3, const float* __restrict__ b3,
    float* __restrict__ out, int t)
{
    __shared__ float hrow[4][512];     // 8 KB
    __shared__ float part[2][4][128];  // 4 KB
    __shared__ float z1s[4][128];      // 2 KB
    __shared__ float z2s[4][128];      // 2 KB
    const int tid = threadIdx.x;
    const int bbase = blockIdx.x * 4;
    const float* __restrict__ h = g_h[sel];

    #pragma unroll
    for (int it = 0; it < 2; ++it) {
        int s = tid + it*256;          // 512 float4 slots
        int b = s >> 7, kq = s & 127;
        ((float4*)hrow[b])[kq] = *(const float4*)(h + (bbase + b)*H + kq*4);
    }
    __syncthreads();

    const int c = tid & 127;
    const int half = tid >> 7;

    // phase 1: z1 = relu(h@W1^T + b1), K=512 split 2x256
    {
        float a0=0.f, a1=0.f, a2=0.f, a3=0.f;
        const float* wr = W1 + c*512 + half*256;
        const int ko = half*256;
        #pragma unroll 4
        for (int k = 0; k < 256; k += 4) {
            float4 w  = *(const float4*)(wr + k);
            float4 x0 = *(const float4*)(&hrow[0][ko + k]);
            float4 x1 = *(const float4*)(&hrow[1][ko + k]);
            float4 x2 = *(const float4*)(&hrow[2][ko + k]);
            float4 x3 = *(const float4*)(&hrow[3][ko + k]);
            a0 += w.x*x0.x + w.y*x0.y + w.z*x0.z + w.w*x0.w;
            a1 += w.x*x1.x + w.y*x1.y + w.z*x1.z + w.w*x1.w;
            a2 += w.x*x2.x + w.y*x2.y + w.z*x2.z + w.w*x2.w;
            a3 += w.x*x3.x + w.y*x3.y + w.z*x3.z + w.w*x3.w;
        }
        part[half][0][c]=a0; part[half][1][c]=a1; part[half][2][c]=a2; part[half][3][c]=a3;
    }
    __syncthreads();
    #pragma unroll
    for (int it = 0; it < 2; ++it) {
        int s = tid + it*256;
        int b = s >> 7, cc = s & 127;
        float v = part[0][b][cc] + part[1][b][cc] + b1[cc];
        z1s[b][cc] = fmaxf(v, 0.0f);
    }
    __syncthreads();

    // phase 2: z2 = relu(z1@W2^T + b2), K=128 split 2x64
    {
        float a0=0.f, a1=0.f, a2=0.f, a3=0.f;
        const float* wr = W2 + c*128 + half*64;
        const int ko = half*64;
        #pragma unroll 4
        for (int k = 0; k < 64; k += 4) {
            float4 w  = *(const float4*)(wr + k);
            float4 x0 = *(const float4*)(&z1s[0][ko + k]);
            float4 x1 = *(const float4*)(&z1s[1][ko + k]);
            float4 x2 = *(const float4*)(&z1s[2][ko + k]);
            float4 x3 = *(const float4*)(&z1s[3][ko + k]);
            a0 += w.x*x0.x + w.y*x0.y + w.z*x0.z + w.w*x0.w;
            a1 += w.x*x1.x + w.y*x1.y + w.z*x1.z + w.w*x1.w;
            a2 += w.x*x2.x + w.y*x2.y + w.z*x2.z + w.w*x2.w;
            a3 += w.x*x3.x + w.y*x3.y + w.z*x3.z + w.w*x3.w;
        }
        part[half][0][c]=a0; part[half][1][c]=a1; part[half][2][c]=a2; part[half][3][c]=a3;
    }
    __syncthreads();
    #pragma unroll
    for (int it = 0; it < 2; ++it) {
        int s = tid + it*256;
        int b = s >> 7, cc = s & 127;
        float v = part[0][b][cc] + part[1][b][cc] + b2[cc];
        z2s[b][cc] = fmaxf(v, 0.0f);
    }
    __syncthreads();

    // phase 3: tok = z2@W3^T + b3, 256 cols (one per thread), K=128
    {
        float a0=0.f, a1=0.f, a2=0.f, a3=0.f;
        const float* wr = W3 + tid*128;
        #pragma unroll 4
        for (int k = 0; k < 128; k += 4) {
            float4 w  = *(const float4*)(wr + k);
            float4 x0 = *(const float4*)(&z2s[0][k]);
            float4 x1 = *(const float4*)(&z2s[1][k]);
            float4 x2 = *(const float4*)(&z2s[2][k]);
            float4 x3 = *(const float4*)(&z2s[3][k]);
            a0 += w.x*x0.x + w.y*x0.y + w.z*x0.z + w.w*x0.w;
            a1 += w.x*x1.x + w.y*x1.y + w.z*x1.z + w.w*x1.w;
            a2 += w.x*x2.x + w.y*x2.y + w.z*x2.z + w.w*x2.w;
            a3 += w.x*x3.x + w.y*x3.y + w.z*x3.z + w.w*x3.w;
        }
        float bias = b3[tid];
        int o = (t+1)*E + tid;
        out[(bbase+0)*LE + o] = a0 + bias;
        out[(bbase+1)*LE + o] = a1 + bias;
        out[(bbase+2)*LE + o] = a2 + bias;
        out[(bbase+3)*LE + o] = a3 + bias;
    }
}

// ---------------------------------------------------------------------------
extern "C" void kernel_launch(void* const* d_in, const int* in_sizes, int n_in,
                              void* d_out, int out_size, void* d_ws, size_t ws_size,
                              hipStream_t stream) {
    (void)in_sizes; (void)n_in; (void)out_size; (void)d_ws; (void)ws_size;
    const float* hidden = (const float*)d_in[0];
    const float* padded = (const float*)d_in[1];
    const float* W_ih   = (const float*)d_in[2];
    const float* W_hh   = (const float*)d_in[3];
    const float* b_ih   = (const float*)d_in[4];
    const float* b_hh   = (const float*)d_in[5];
    const float* W1     = (const float*)d_in[6];
    const float* b1     = (const float*)d_in[7];
    const float* W2     = (const float*)d_in[8];
    const float* b2     = (const float*)d_in[9];
    const float* W3     = (const float*)d_in[10];
    const float* b3     = (const float*)d_in[11];
    float* out = (float*)d_out;

    init_kernel<<<2048, 256, 0, stream>>>(hidden, out);
    for (int t = 0; t < L-1; ++t) {
        gates_kernel<<<dim3(16,16), 512, 0, stream>>>(
            padded, t, W_ih, W_hh, b_ih, b_hh);
        mlp_kernel<<<256, 256, 0, stream>>>(
            (t & 1) ^ 1, W1, b1, W2, b2, W3, b3, out, t);
    }
}

// Round 3
// 4395.211 us; speedup vs baseline: 4.1646x; 4.1646x over previous
//
#include <hip/hip_runtime.h>
#include <math.h>
#include <stdint.h>

#define B 1024
#define H 512
#define E 256
#define L 128
#define LE (L*E)   // 32768

typedef _Float16 f16;
typedef _Float16 f16x8 __attribute__((ext_vector_type(8)));
typedef float f32x4 __attribute__((ext_vector_type(4)));
typedef const __attribute__((address_space(1))) uint32_t gu32;
typedef __attribute__((address_space(3))) uint32_t lu32;

// ---------------------------------------------------------------------------
// Persistent state in module device globals (round-1 lesson: d_ws was unsafe).
// All buffers are fully rewritten every call -> deterministic graph replays.
// ---------------------------------------------------------------------------
__device__ __align__(16) float g_h[2][B*H];       // fp32 h for MLP
__device__ __align__(16) float g_c[B*H];          // fp32 c
// Pre-swizzled fp16 tile images for global_load_lds staging (swizzle baked
// into the GLOBAL layout; ds_read applies the same XOR -> conflict-free).
// X: [t:127][mt:16][kt:4] images of 64 rows x 64 k (8 KB each)
__device__ __align__(16) f16 g_Xs[127*16*4*4096];
// H: double-buffered [2][mt:16][kt:8] images of 64x64
__device__ __align__(16) f16 g_Hs[2][16*8*4096];
// W': rows reordered n = j*4 + gate; [nt:16][kt:12] images of 128 x 64 (16 KB)
__device__ __align__(16) f16 g_Ws[16*12*8192];
__device__ __align__(16) float g_bsum[2048];      // b_ih+b_hh, reordered n=j*4+g

__device__ __forceinline__ float sigm(float x) { return 1.0f / (1.0f + expf(-x)); }

// ---------------------------------------------------------------------------
// conv_w: W' fp16 tile images (reordered, swizzled) + bias sums
// ---------------------------------------------------------------------------
__global__ __launch_bounds__(256) void conv_w(
    const float* __restrict__ W_ih, const float* __restrict__ W_hh,
    const float* __restrict__ b_ih, const float* __restrict__ b_hh)
{
    int gid = blockIdx.x*256 + threadIdx.x;   // 16*12*128*8 = 196608 threads
    int kb  = gid & 7;
    int r1  = gid >> 3;
    int row = r1 & 127;
    int r2  = r1 >> 7;
    int kt  = r2 % 12;
    int nt  = r2 / 12;
    int n = nt*128 + row;
    int g = n & 3, j = n >> 2;
    int wrow = g*512 + j;
    int k = kt*64 + kb*8;
    const float* src = (k < 256) ? (W_ih + wrow*256 + k)
                                 : (W_hh + wrow*512 + (k - 256));
    f16x8 v;
    #pragma unroll
    for (int e = 0; e < 8; ++e) v[e] = (f16)src[e];
    char* dst = (char*)g_Ws + (size_t)(nt*12 + kt)*16384
              + row*128 + ((kb*16) ^ ((row & 7) << 4));
    *(f16x8*)dst = v;
    if (gid < 2048) {
        int gg = gid & 3, jj = gid >> 2;
        g_bsum[gid] = b_ih[gg*512 + jj] + b_hh[gg*512 + jj];
    }
}

// ---------------------------------------------------------------------------
// conv_x: X fp16 tile images for all 127 steps
// ---------------------------------------------------------------------------
__global__ __launch_bounds__(256) void conv_x(const float* __restrict__ padded)
{
    int gid = blockIdx.x*256 + threadIdx.x;   // 127*16*4*64*8 = 4161536
    int kb  = gid & 7;
    int r1  = gid >> 3;
    int row = r1 & 63;
    int r2  = r1 >> 6;
    int kt  = r2 & 3;
    int r3  = r2 >> 2;
    int mt  = r3 & 15;
    int t   = r3 >> 4;
    if (t >= 127) return;
    int b = mt*64 + row;
    int k = kt*64 + kb*8;
    const float* src = padded + (size_t)b*LE + t*E + k;
    f16x8 v;
    #pragma unroll
    for (int e = 0; e < 8; ++e) v[e] = (f16)src[e];
    char* dst = (char*)g_Xs + (size_t)((t*16 + mt)*4 + kt)*8192
              + row*128 + ((kb*16) ^ ((row & 7) << 4));
    *(f16x8*)dst = v;
}

// ---------------------------------------------------------------------------
// init: h[0], c, H-image[0], out row 0
// ---------------------------------------------------------------------------
__global__ __launch_bounds__(256) void init_kernel(
    const float* __restrict__ hidden, float* __restrict__ out)
{
    int i = blockIdx.x * 256 + threadIdx.x;
    if (i < B*H) {
        float hv = hidden[i];
        g_h[0][i] = hv; g_c[i] = 0.0f;
        int b = i >> 9, j = i & 511;
        int mt = b >> 6, row = b & 63, kt = j >> 6, kk = j & 63;
        char* dst = (char*)&g_Hs[0][0] + (size_t)(mt*8 + kt)*8192
                  + row*128 + ((kk*2) ^ ((row & 7) << 4));
        *(f16*)dst = (f16)hv;
    }
    if (i < B*E) {
        int b = i >> 8, e = i & 255;
        out[b*LE + e] = (e == 0) ? 1.0f : 0.0f;
    }
}

// ---------------------------------------------------------------------------
// gates_mfma: C(1024x2048) = A(1024x768 fp16) x W'^T, fused LSTM cell update.
// Tile 64(M) x 128(N), BK=64, 512 threads = 8 waves (2x4), wave = 32x32 via
// 2x2 frags of mfma_f32_16x16x32_f16. Staging via global_load_lds from the
// pre-swizzled images; ds_read_b128 with matching XOR (conflict-free).
// Epilogue: acc -> Glds (all 4 gates adjacent: n=j*4+g), cell update, h out
// as fp32 (MLP) + fp16 image (next step's A).
// ---------------------------------------------------------------------------
__global__ __launch_bounds__(512) void gates_mfma(int t)
{
    __shared__ char  ldsA[8192];
    __shared__ char  ldsB[16384];
    __shared__ float Glds[64][132];   // +4 pad: write conflicts 2-way (free)
    const int tid  = threadIdx.x;
    const int lane = tid & 63;
    const int w    = tid >> 6;        // 0..7
    const int mt   = blockIdx.x;      // 0..15 (batch/64)
    const int nt   = blockIdx.y;      // 0..15 (gate-n/128)
    const int cur  = t & 1, nxt = cur ^ 1;
    const int wr   = w >> 2;          // 0..1
    const int wc   = w & 3;           // 0..3

    f32x4 acc[2][2];
    #pragma unroll
    for (int m = 0; m < 2; ++m)
        #pragma unroll
        for (int n = 0; n < 2; ++n) acc[m][n] = (f32x4){0.f, 0.f, 0.f, 0.f};

    const char* gW = (const char*)g_Ws + (size_t)(nt*12)*16384;

    for (int kt = 0; kt < 12; ++kt) {
        const char* gA = (kt < 4)
            ? (const char*)g_Xs + (size_t)((t*16 + mt)*4 + kt)*8192
            : (const char*)&g_Hs[cur][0] + (size_t)(mt*8 + (kt - 4))*8192;
        // stage A: 8 x 1024B chunks, one per wave
        __builtin_amdgcn_global_load_lds(
            (gu32*)(gA + w*1024 + lane*16),
            (lu32*)(ldsA + w*1024 + lane*16), 16, 0, 0);
        // stage B: 16 chunks, two per wave
        const char* gB = gW + (size_t)kt*16384;
        #pragma unroll
        for (int it = 0; it < 2; ++it) {
            int c = w + it*8;
            __builtin_amdgcn_global_load_lds(
                (gu32*)(gB + c*1024 + lane*16),
                (lu32*)(ldsB + c*1024 + lane*16), 16, 0, 0);
        }
        __syncthreads();
        #pragma unroll
        for (int kk = 0; kk < 2; ++kk) {
            const int kb0 = kk*64 + ((lane >> 4) << 4);  // kbyte
            int ar0 = wr*32 + (lane & 15);
            int ar1 = ar0 + 16;
            f16x8 a0 = *(const f16x8*)(ldsA + ar0*128 + (kb0 ^ ((ar0 & 7) << 4)));
            f16x8 a1 = *(const f16x8*)(ldsA + ar1*128 + (kb0 ^ ((ar1 & 7) << 4)));
            int br0 = wc*32 + (lane & 15);
            int br1 = br0 + 16;
            f16x8 b0 = *(const f16x8*)(ldsB + br0*128 + (kb0 ^ ((br0 & 7) << 4)));
            f16x8 b1 = *(const f16x8*)(ldsB + br1*128 + (kb0 ^ ((br1 & 7) << 4)));
            acc[0][0] = __builtin_amdgcn_mfma_f32_16x16x32_f16(a0, b0, acc[0][0], 0, 0, 0);
            acc[0][1] = __builtin_amdgcn_mfma_f32_16x16x32_f16(a0, b1, acc[0][1], 0, 0, 0);
            acc[1][0] = __builtin_amdgcn_mfma_f32_16x16x32_f16(a1, b0, acc[1][0], 0, 0, 0);
            acc[1][1] = __builtin_amdgcn_mfma_f32_16x16x32_f16(a1, b1, acc[1][1], 0, 0, 0);
        }
        __syncthreads();
    }

    // acc -> Glds  (C/D layout: col = lane&15, row = (lane>>4)*4 + reg)
    #pragma unroll
    for (int m = 0; m < 2; ++m)
        #pragma unroll
        for (int n = 0; n < 2; ++n)
            #pragma unroll
            for (int i = 0; i < 4; ++i) {
                int row = wr*32 + m*16 + ((lane >> 4) << 2) + i;
                int col = wc*32 + n*16 + (lane & 15);
                Glds[row][col] = acc[m][n][i];
            }
    __syncthreads();

    // cell update: 2048 cells (64 b x 32 j), 4 per thread
    #pragma unroll
    for (int i = 0; i < 4; ++i) {
        int cell = tid + i*512;
        int bl = cell >> 5, jl = cell & 31;
        float4 gv = *(const float4*)&Glds[bl][jl*4];
        float4 bs = *(const float4*)&g_bsum[nt*128 + jl*4];
        float iv = sigm(gv.x + bs.x);
        float fv = sigm(gv.y + bs.y);
        float gg = tanhf(gv.z + bs.z);
        float ov = sigm(gv.w + bs.w);
        int bg = mt*64 + bl, jg = nt*32 + jl;
        int idx = bg*H + jg;
        float cv = fv * g_c[idx] + iv * gg;
        g_c[idx] = cv;
        float hv = ov * tanhf(cv);
        g_h[nxt][idx] = hv;
        int ktl = jg >> 6, kkk = jg & 63;
        char* hd = (char*)&g_Hs[nxt][0] + (size_t)(mt*8 + ktl)*8192
                 + bl*128 + ((kkk*2) ^ ((bl & 7) << 4));
        *(f16*)hd = (f16)hv;
    }
}

// ---------------------------------------------------------------------------
// mlp: unchanged fp32 path (4 batch rows / block)
// ---------------------------------------------------------------------------
__global__ __launch_bounds__(256) void mlp_kernel(
    int sel,
    const float* __restrict__ W1, const float* __restrict__ b1,
    const float* __restrict__ W2, const float* __restrict__ b2,
    const float* __restrict__ W3, const float* __restrict__ b3,
    float* __restrict__ out, int t)
{
    __shared__ float hrow[4][512];
    __shared__ float part[2][4][128];
    __shared__ float z1s[4][128];
    __shared__ float z2s[4][128];
    const int tid = threadIdx.x;
    const int bbase = blockIdx.x * 4;
    const float* __restrict__ h = g_h[sel];

    #pragma unroll
    for (int it = 0; it < 2; ++it) {
        int s = tid + it*256;
        int b = s >> 7, kq = s & 127;
        ((float4*)hrow[b])[kq] = *(const float4*)(h + (bbase + b)*H + kq*4);
    }
    __syncthreads();

    const int c = tid & 127;
    const int half = tid >> 7;

    {   // z1 = relu(h@W1^T + b1), K=512 split 2x256
        float a0=0.f, a1=0.f, a2=0.f, a3=0.f;
        const float* wr = W1 + c*512 + half*256;
        const int ko = half*256;
        #pragma unroll 4
        for (int k = 0; k < 256; k += 4) {
            float4 w  = *(const float4*)(wr + k);
            float4 x0 = *(const float4*)(&hrow[0][ko + k]);
            float4 x1 = *(const float4*)(&hrow[1][ko + k]);
            float4 x2 = *(const float4*)(&hrow[2][ko + k]);
            float4 x3 = *(const float4*)(&hrow[3][ko + k]);
            a0 += w.x*x0.x + w.y*x0.y + w.z*x0.z + w.w*x0.w;
            a1 += w.x*x1.x + w.y*x1.y + w.z*x1.z + w.w*x1.w;
            a2 += w.x*x2.x + w.y*x2.y + w.z*x2.z + w.w*x2.w;
            a3 += w.x*x3.x + w.y*x3.y + w.z*x3.z + w.w*x3.w;
        }
        part[half][0][c]=a0; part[half][1][c]=a1; part[half][2][c]=a2; part[half][3][c]=a3;
    }
    __syncthreads();
    #pragma unroll
    for (int it = 0; it < 2; ++it) {
        int s = tid + it*256;
        int b = s >> 7, cc = s & 127;
        float v = part[0][b][cc] + part[1][b][cc] + b1[cc];
        z1s[b][cc] = fmaxf(v, 0.0f);
    }
    __syncthreads();

    {   // z2 = relu(z1@W2^T + b2), K=128 split 2x64
        float a0=0.f, a1=0.f, a2=0.f, a3=0.f;
        const float* wr = W2 + c*128 + half*64;
        const int ko = half*64;
        #pragma unroll 4
        for (int k = 0; k < 64; k += 4) {
            float4 w  = *(const float4*)(wr + k);
            float4 x0 = *(const float4*)(&z1s[0][ko + k]);
            float4 x1 = *(const float4*)(&z1s[1][ko + k]);
            float4 x2 = *(const float4*)(&z1s[2][ko + k]);
            float4 x3 = *(const float4*)(&z1s[3][ko + k]);
            a0 += w.x*x0.x + w.y*x0.y + w.z*x0.z + w.w*x0.w;
            a1 += w.x*x1.x + w.y*x1.y + w.z*x1.z + w.w*x1.w;
            a2 += w.x*x2.x + w.y*x2.y + w.z*x2.z + w.w*x2.w;
            a3 += w.x*x3.x + w.y*x3.y + w.z*x3.z + w.w*x3.w;
        }
        part[half][0][c]=a0; part[half][1][c]=a1; part[half][2][c]=a2; part[half][3][c]=a3;
    }
    __syncthreads();
    #pragma unroll
    for (int it = 0; it < 2; ++it) {
        int s = tid + it*256;
        int b = s >> 7, cc = s & 127;
        float v = part[0][b][cc] + part[1][b][cc] + b2[cc];
        z2s[b][cc] = fmaxf(v, 0.0f);
    }
    __syncthreads();

    {   // tok = z2@W3^T + b3
        float a0=0.f, a1=0.f, a2=0.f, a3=0.f;
        const float* wr = W3 + tid*128;
        #pragma unroll 4
        for (int k = 0; k < 128; k += 4) {
            float4 w  = *(const float4*)(wr + k);
            float4 x0 = *(const float4*)(&z2s[0][k]);
            float4 x1 = *(const float4*)(&z2s[1][k]);
            float4 x2 = *(const float4*)(&z2s[2][k]);
            float4 x3 = *(const float4*)(&z2s[3][k]);
            a0 += w.x*x0.x + w.y*x0.y + w.z*x0.z + w.w*x0.w;
            a1 += w.x*x1.x + w.y*x1.y + w.z*x1.z + w.w*x1.w;
            a2 += w.x*x2.x + w.y*x2.y + w.z*x2.z + w.w*x2.w;
            a3 += w.x*x3.x + w.y*x3.y + w.z*x3.z + w.w*x3.w;
        }
        float bias = b3[tid];
        int o = (t+1)*E + tid;
        out[(bbase+0)*LE + o] = a0 + bias;
        out[(bbase+1)*LE + o] = a1 + bias;
        out[(bbase+2)*LE + o] = a2 + bias;
        out[(bbase+3)*LE + o] = a3 + bias;
    }
}

// ---------------------------------------------------------------------------
extern "C" void kernel_launch(void* const* d_in, const int* in_sizes, int n_in,
                              void* d_out, int out_size, void* d_ws, size_t ws_size,
                              hipStream_t stream) {
    (void)in_sizes; (void)n_in; (void)out_size; (void)d_ws; (void)ws_size;
    const float* hidden = (const float*)d_in[0];
    const float* padded = (const float*)d_in[1];
    const float* W_ih   = (const float*)d_in[2];
    const float* W_hh   = (const float*)d_in[3];
    const float* b_ih   = (const float*)d_in[4];
    const float* b_hh   = (const float*)d_in[5];
    const float* W1     = (const float*)d_in[6];
    const float* b1     = (const float*)d_in[7];
    const float* W2     = (const float*)d_in[8];
    const float* b2     = (const float*)d_in[9];
    const float* W3     = (const float*)d_in[10];
    const float* b3     = (const float*)d_in[11];
    float* out = (float*)d_out;

    conv_w<<<768, 256, 0, stream>>>(W_ih, W_hh, b_ih, b_hh);
    conv_x<<<16256, 256, 0, stream>>>(padded);
    init_kernel<<<2048, 256, 0, stream>>>(hidden, out);
    for (int t = 0; t < L-1; ++t) {
        gates_mfma<<<dim3(16,16), 512, 0, stream>>>(t);
        mlp_kernel<<<256, 256, 0, stream>>>(
            (t & 1) ^ 1, W1, b1, W2, b2, W3, b3, out, t);
    }
}

// Round 4
// 2749.835 us; speedup vs baseline: 6.6565x; 1.5984x over previous
//
#include <hip/hip_runtime.h>
#include <math.h>
#include <stdint.h>

#define B 1024
#define H 512
#define E 256
#define L 128
#define LE (L*E)   // 32768

typedef _Float16 f16;
typedef _Float16 f16x8 __attribute__((ext_vector_type(8)));
typedef float f32x4 __attribute__((ext_vector_type(4)));
typedef const __attribute__((address_space(1))) uint32_t gu32;
typedef __attribute__((address_space(3))) uint32_t lu32;

// ---------------------------------------------------------------------------
// Persistent state in module device globals (round-1 lesson: d_ws unsafe).
// All buffers fully rewritten every call -> deterministic graph replays.
// ---------------------------------------------------------------------------
__device__ __align__(16) float g_c[B*H];          // fp32 c
// Pre-swizzled fp16 tile images (swizzle baked into GLOBAL layout; ds_read
// applies the same XOR -> conflict-free; global_load_lds stays linear).
__device__ __align__(16) f16 g_Xs[127*16*4*4096]; // X: [t][mt:16][kt:4] 64x64
__device__ __align__(16) f16 g_Hs[2][16*8*4096];  // H: dbuf [mt:16][kt:8] 64x64
__device__ __align__(16) f16 g_Ws[16*12*8192];    // gates W' [nt:16][kt:12] 128x64
__device__ __align__(16) f16 g_W1s[8*8192];       // W1' [kt:8] 128x64
__device__ __align__(16) f16 g_W2s[2*8192];       // W2' [kt:2] 128x64
__device__ __align__(16) f16 g_W3s[4*8192];       // W3' [nh:2][kt:2] 128x64
__device__ __align__(16) float g_bsum[2048];      // b_ih+b_hh, n=j*4+g order

__device__ __forceinline__ float sigm(float x) { return 1.0f / (1.0f + expf(-x)); }

// ---------------------------------------------------------------------------
// conv_w: gates W' fp16 tile images (gate-interleaved n=j*4+g) + bias sums
// ---------------------------------------------------------------------------
__global__ __launch_bounds__(256) void conv_w(
    const float* __restrict__ W_ih, const float* __restrict__ W_hh,
    const float* __restrict__ b_ih, const float* __restrict__ b_hh)
{
    int gid = blockIdx.x*256 + threadIdx.x;   // 16*12*128*8 = 196608
    int kb  = gid & 7;
    int r1  = gid >> 3;
    int row = r1 & 127;
    int r2  = r1 >> 7;
    int kt  = r2 % 12;
    int nt  = r2 / 12;
    int n = nt*128 + row;
    int g = n & 3, j = n >> 2;
    int wrow = g*512 + j;
    int k = kt*64 + kb*8;
    const float* src = (k < 256) ? (W_ih + wrow*256 + k)
                                 : (W_hh + wrow*512 + (k - 256));
    f16x8 v;
    #pragma unroll
    for (int e = 0; e < 8; ++e) v[e] = (f16)src[e];
    char* dst = (char*)g_Ws + (size_t)(nt*12 + kt)*16384
              + row*128 + ((kb*16) ^ ((row & 7) << 4));
    *(f16x8*)dst = v;
    if (gid < 2048) {
        int gg = gid & 3, jj = gid >> 2;
        g_bsum[gid] = b_ih[gg*512 + jj] + b_hh[gg*512 + jj];
    }
}

// ---------------------------------------------------------------------------
// conv_mlp: W1/W2/W3 fp16 tile images (plain n order)
// ---------------------------------------------------------------------------
__global__ __launch_bounds__(256) void conv_mlp(
    const float* __restrict__ W1, const float* __restrict__ W2,
    const float* __restrict__ W3)
{
    int gid = blockIdx.x*256 + threadIdx.x;   // 14336 threads
    if (gid < 8192) {                         // W1 (128,512) -> 8 tiles
        int s = gid;
        int kb = s & 7, row = (s >> 3) & 127, kt = s >> 10;
        const float* src = W1 + row*512 + kt*64 + kb*8;
        f16x8 v;
        #pragma unroll
        for (int e = 0; e < 8; ++e) v[e] = (f16)src[e];
        char* dst = (char*)g_W1s + (size_t)kt*16384
                  + row*128 + ((kb*16) ^ ((row & 7) << 4));
        *(f16x8*)dst = v;
    } else if (gid < 10240) {                 // W2 (128,128) -> 2 tiles
        int s = gid - 8192;
        int kb = s & 7, row = (s >> 3) & 127, kt = s >> 10;
        const float* src = W2 + row*128 + kt*64 + kb*8;
        f16x8 v;
        #pragma unroll
        for (int e = 0; e < 8; ++e) v[e] = (f16)src[e];
        char* dst = (char*)g_W2s + (size_t)kt*16384
                  + row*128 + ((kb*16) ^ ((row & 7) << 4));
        *(f16x8*)dst = v;
    } else if (gid < 14336) {                 // W3 (256,128) -> [nh:2][kt:2]
        int s = gid - 10240;
        int kb = s & 7, r256 = (s >> 3) & 255, kt = s >> 11;
        int nh = r256 >> 7, row = r256 & 127;
        const float* src = W3 + r256*128 + kt*64 + kb*8;
        f16x8 v;
        #pragma unroll
        for (int e = 0; e < 8; ++e) v[e] = (f16)src[e];
        char* dst = (char*)g_W3s + (size_t)(nh*2 + kt)*16384
                  + row*128 + ((kb*16) ^ ((row & 7) << 4));
        *(f16x8*)dst = v;
    }
}

// ---------------------------------------------------------------------------
// conv_x: X fp16 tile images for all 127 steps
// ---------------------------------------------------------------------------
__global__ __launch_bounds__(256) void conv_x(const float* __restrict__ padded)
{
    int gid = blockIdx.x*256 + threadIdx.x;   // 127*16*4*64*8 = 4161536
    int kb  = gid & 7;
    int r1  = gid >> 3;
    int row = r1 & 63;
    int r2  = r1 >> 6;
    int kt  = r2 & 3;
    int r3  = r2 >> 2;
    int mt  = r3 & 15;
    int t   = r3 >> 4;
    if (t >= 127) return;
    int b = mt*64 + row;
    int k = kt*64 + kb*8;
    const float* src = padded + (size_t)b*LE + t*E + k;
    f16x8 v;
    #pragma unroll
    for (int e = 0; e < 8; ++e) v[e] = (f16)src[e];
    char* dst = (char*)g_Xs + (size_t)((t*16 + mt)*4 + kt)*8192
              + row*128 + ((kb*16) ^ ((row & 7) << 4));
    *(f16x8*)dst = v;
}

// ---------------------------------------------------------------------------
// init: c <- 0, H-image[0] <- hidden, out row 0 <- one-hot
// ---------------------------------------------------------------------------
__global__ __launch_bounds__(256) void init_kernel(
    const float* __restrict__ hidden, float* __restrict__ out)
{
    int i = blockIdx.x * 256 + threadIdx.x;
    if (i < B*H) {
        float hv = hidden[i];
        g_c[i] = 0.0f;
        int b = i >> 9, j = i & 511;
        int mt = b >> 6, row = b & 63, kt = j >> 6, kk = j & 63;
        char* dst = (char*)&g_Hs[0][0] + (size_t)(mt*8 + kt)*8192
                  + row*128 + ((kk*2) ^ ((row & 7) << 4));
        *(f16*)dst = (f16)hv;
    }
    if (i < B*E) {
        int b = i >> 8, e = i & 255;
        out[b*LE + e] = (e == 0) ? 1.0f : 0.0f;
    }
}

// ---------------------------------------------------------------------------
// gates_mfma: unchanged structure from round 3 (works); g_h store removed.
// ---------------------------------------------------------------------------
__global__ __launch_bounds__(512) void gates_mfma(int t)
{
    __shared__ char  ldsA[8192];
    __shared__ char  ldsB[16384];
    __shared__ float Glds[64][132];
    const int tid  = threadIdx.x;
    const int lane = tid & 63;
    const int w    = tid >> 6;
    const int mt   = blockIdx.x;
    const int nt   = blockIdx.y;
    const int cur  = t & 1, nxt = cur ^ 1;
    const int wr   = w >> 2;
    const int wc   = w & 3;

    f32x4 acc[2][2];
    #pragma unroll
    for (int m = 0; m < 2; ++m)
        #pragma unroll
        for (int n = 0; n < 2; ++n) acc[m][n] = (f32x4){0.f, 0.f, 0.f, 0.f};

    const char* gW = (const char*)g_Ws + (size_t)(nt*12)*16384;

    for (int kt = 0; kt < 12; ++kt) {
        const char* gA = (kt < 4)
            ? (const char*)g_Xs + (size_t)((t*16 + mt)*4 + kt)*8192
            : (const char*)&g_Hs[cur][0] + (size_t)(mt*8 + (kt - 4))*8192;
        __builtin_amdgcn_global_load_lds(
            (gu32*)(gA + w*1024 + lane*16),
            (lu32*)(ldsA + w*1024 + lane*16), 16, 0, 0);
        const char* gB = gW + (size_t)kt*16384;
        #pragma unroll
        for (int it = 0; it < 2; ++it) {
            int c = w + it*8;
            __builtin_amdgcn_global_load_lds(
                (gu32*)(gB + c*1024 + lane*16),
                (lu32*)(ldsB + c*1024 + lane*16), 16, 0, 0);
        }
        __syncthreads();
        #pragma unroll
        for (int kk = 0; kk < 2; ++kk) {
            const int kb0 = kk*64 + ((lane >> 4) << 4);
            int ar0 = wr*32 + (lane & 15);
            int ar1 = ar0 + 16;
            f16x8 a0 = *(const f16x8*)(ldsA + ar0*128 + (kb0 ^ ((ar0 & 7) << 4)));
            f16x8 a1 = *(const f16x8*)(ldsA + ar1*128 + (kb0 ^ ((ar1 & 7) << 4)));
            int br0 = wc*32 + (lane & 15);
            int br1 = br0 + 16;
            f16x8 b0 = *(const f16x8*)(ldsB + br0*128 + (kb0 ^ ((br0 & 7) << 4)));
            f16x8 b1 = *(const f16x8*)(ldsB + br1*128 + (kb0 ^ ((br1 & 7) << 4)));
            acc[0][0] = __builtin_amdgcn_mfma_f32_16x16x32_f16(a0, b0, acc[0][0], 0, 0, 0);
            acc[0][1] = __builtin_amdgcn_mfma_f32_16x16x32_f16(a0, b1, acc[0][1], 0, 0, 0);
            acc[1][0] = __builtin_amdgcn_mfma_f32_16x16x32_f16(a1, b0, acc[1][0], 0, 0, 0);
            acc[1][1] = __builtin_amdgcn_mfma_f32_16x16x32_f16(a1, b1, acc[1][1], 0, 0, 0);
        }
        __syncthreads();
    }

    #pragma unroll
    for (int m = 0; m < 2; ++m)
        #pragma unroll
        for (int n = 0; n < 2; ++n)
            #pragma unroll
            for (int i = 0; i < 4; ++i) {
                int row = wr*32 + m*16 + ((lane >> 4) << 2) + i;
                int col = wc*32 + n*16 + (lane & 15);
                Glds[row][col] = acc[m][n][i];
            }
    __syncthreads();

    #pragma unroll
    for (int i = 0; i < 4; ++i) {
        int cell = tid + i*512;
        int bl = cell >> 5, jl = cell & 31;
        float4 gv = *(const float4*)&Glds[bl][jl*4];
        float4 bs = *(const float4*)&g_bsum[nt*128 + jl*4];
        float iv = sigm(gv.x + bs.x);
        float fv = sigm(gv.y + bs.y);
        float gg = tanhf(gv.z + bs.z);
        float ov = sigm(gv.w + bs.w);
        int bg = mt*64 + bl, jg = nt*32 + jl;
        int idx = bg*H + jg;
        float cv = fv * g_c[idx] + iv * gg;
        g_c[idx] = cv;
        float hv = ov * tanhf(cv);
        int ktl = jg >> 6, kkk = jg & 63;
        char* hd = (char*)&g_Hs[nxt][0] + (size_t)(mt*8 + ktl)*8192
                 + bl*128 + ((kkk*2) ^ ((bl & 7) << 4));
        *(f16*)hd = (f16)hv;
    }
}

// ---------------------------------------------------------------------------
// mlp_mfma: fused 3-layer MLP, 16 blocks x 256 thr (4 waves). Wave w covers
// N cols [w*32, w*32+32), all 64 M rows (4x2 frags -> 6 ds_read per 8 MFMA).
// LDS 64KB: W dbuf 32K | A dbuf 16K (reused as Z2) | Z1 16K.
// Layer1 uses the minimal 2-phase dbuf (stage kt+1 before compute kt, one
// barrier per iter). z1/z2 stored as swizzled f16 LDS images, re-read as
// next layer's A-frags.
// ---------------------------------------------------------------------------
__global__ __launch_bounds__(256) void mlp_mfma(
    int sel,
    const float* __restrict__ b1, const float* __restrict__ b2,
    const float* __restrict__ b3, float* __restrict__ out, int t)
{
    __shared__ char lds[65536];
    char* Wb = lds;            // 2 x 16384 (W tile dbuf)
    char* Ab = lds + 32768;    // 2 x 8192  (A tile dbuf; Z2 images later)
    char* Z1 = lds + 49152;    // 2 x 8192  (z1 images)
    const int tid  = threadIdx.x;
    const int lane = tid & 63;
    const int w    = tid >> 6;       // 0..3 = wave N strip
    const int mt   = blockIdx.x;     // 0..15

    const char* gH = (const char*)&g_Hs[sel][0] + (size_t)mt*8*8192;

    float b1v[2], b2v[2], b3v[2][2];
    #pragma unroll
    for (int n = 0; n < 2; ++n) {
        int col = w*32 + n*16 + (lane & 15);
        b1v[n] = b1[col]; b2v[n] = b2[col];
        b3v[0][n] = b3[col]; b3v[1][n] = b3[128 + col];
    }

    const int kb0_0 = ((lane >> 4) << 4);    // k-byte base within 64k tile

    // ---- layer 1: z1 = relu(h @ W1^T + b1), K=512 (8 kt), N=128 ----
    f32x4 acc[4][2];
    #pragma unroll
    for (int m = 0; m < 4; ++m) { acc[m][0] = (f32x4){0,0,0,0}; acc[m][1] = (f32x4){0,0,0,0}; }

    // prologue: stage kt=0 into buf 0
    #pragma unroll
    for (int it = 0; it < 2; ++it) {
        int c = w*2 + it;
        __builtin_amdgcn_global_load_lds((gu32*)(gH + c*1024 + lane*16),
                                         (lu32*)(Ab + c*1024 + lane*16), 16, 0, 0);
    }
    #pragma unroll
    for (int it = 0; it < 4; ++it) {
        int c = w*4 + it;
        __builtin_amdgcn_global_load_lds((gu32*)((const char*)g_W1s + c*1024 + lane*16),
                                         (lu32*)(Wb + c*1024 + lane*16), 16, 0, 0);
    }
    __syncthreads();

    for (int kt = 0; kt < 8; ++kt) {
        const int cur = kt & 1;
        if (kt < 7) {
            const char* gA = gH + (size_t)(kt+1)*8192;
            const char* gW = (const char*)g_W1s + (size_t)(kt+1)*16384;
            char* dA = Ab + (cur^1)*8192;
            char* dW = Wb + (cur^1)*16384;
            #pragma unroll
            for (int it = 0; it < 2; ++it) {
                int c = w*2 + it;
                __builtin_amdgcn_global_load_lds((gu32*)(gA + c*1024 + lane*16),
                                                 (lu32*)(dA + c*1024 + lane*16), 16, 0, 0);
            }
            #pragma unroll
            for (int it = 0; it < 4; ++it) {
                int c = w*4 + it;
                __builtin_amdgcn_global_load_lds((gu32*)(gW + c*1024 + lane*16),
                                                 (lu32*)(dW + c*1024 + lane*16), 16, 0, 0);
            }
        }
        const char* Ar = Ab + cur*8192;
        const char* Br = Wb + cur*16384;
        #pragma unroll
        for (int kk = 0; kk < 2; ++kk) {
            const int kb0 = kk*64 + kb0_0;
            f16x8 a[4], b[2];
            #pragma unroll
            for (int m = 0; m < 4; ++m) {
                int ar = m*16 + (lane & 15);
                a[m] = *(const f16x8*)(Ar + ar*128 + (kb0 ^ ((ar & 7) << 4)));
            }
            #pragma unroll
            for (int n = 0; n < 2; ++n) {
                int br = w*32 + n*16 + (lane & 15);
                b[n] = *(const f16x8*)(Br + br*128 + (kb0 ^ ((br & 7) << 4)));
            }
            #pragma unroll
            for (int m = 0; m < 4; ++m)
                #pragma unroll
                for (int n = 0; n < 2; ++n)
                    acc[m][n] = __builtin_amdgcn_mfma_f32_16x16x32_f16(a[m], b[n], acc[m][n], 0, 0, 0);
        }
        __syncthreads();
    }

    // z1 -> relu + bias -> f16 swizzled images in Z1
    #pragma unroll
    for (int m = 0; m < 4; ++m)
        #pragma unroll
        for (int n = 0; n < 2; ++n)
            #pragma unroll
            for (int i = 0; i < 4; ++i) {
                int row = m*16 + ((lane >> 4) << 2) + i;
                int col = w*32 + n*16 + (lane & 15);
                float v = fmaxf(acc[m][n][i] + b1v[n], 0.0f);
                int ktz = col >> 6, kkz = col & 63;
                *(f16*)(Z1 + ktz*8192 + row*128 + ((kkz*2) ^ ((row & 7) << 4))) = (f16)v;
            }
    __syncthreads();

    // ---- layer 2: z2 = relu(z1 @ W2^T + b2), K=128 (2 kt in LDS), N=128 ----
    #pragma unroll
    for (int it = 0; it < 8; ++it) {   // stage both W2 tiles (32 KB)
        int c = w*8 + it;
        __builtin_amdgcn_global_load_lds((gu32*)((const char*)g_W2s + c*1024 + lane*16),
                                         (lu32*)(Wb + c*1024 + lane*16), 16, 0, 0);
    }
    __syncthreads();
    #pragma unroll
    for (int m = 0; m < 4; ++m) { acc[m][0] = (f32x4){0,0,0,0}; acc[m][1] = (f32x4){0,0,0,0}; }
    #pragma unroll
    for (int kt = 0; kt < 2; ++kt) {
        #pragma unroll
        for (int kk = 0; kk < 2; ++kk) {
            const int kb0 = kk*64 + kb0_0;
            f16x8 a[4], b[2];
            #pragma unroll
            for (int m = 0; m < 4; ++m) {
                int ar = m*16 + (lane & 15);
                a[m] = *(const f16x8*)(Z1 + kt*8192 + ar*128 + (kb0 ^ ((ar & 7) << 4)));
            }
            #pragma unroll
            for (int n = 0; n < 2; ++n) {
                int br = w*32 + n*16 + (lane & 15);
                b[n] = *(const f16x8*)(Wb + kt*16384 + br*128 + (kb0 ^ ((br & 7) << 4)));
            }
            #pragma unroll
            for (int m = 0; m < 4; ++m)
                #pragma unroll
                for (int n = 0; n < 2; ++n)
                    acc[m][n] = __builtin_amdgcn_mfma_f32_16x16x32_f16(a[m], b[n], acc[m][n], 0, 0, 0);
        }
    }
    __syncthreads();   // Wb free; Ab (A dbuf) dead -> reuse as Z2

    // z2 -> relu + bias -> f16 images in Ab
    #pragma unroll
    for (int m = 0; m < 4; ++m)
        #pragma unroll
        for (int n = 0; n < 2; ++n)
            #pragma unroll
            for (int i = 0; i < 4; ++i) {
                int row = m*16 + ((lane >> 4) << 2) + i;
                int col = w*32 + n*16 + (lane & 15);
                float v = fmaxf(acc[m][n][i] + b2v[n], 0.0f);
                int ktz = col >> 6, kkz = col & 63;
                *(f16*)(Ab + ktz*8192 + row*128 + ((kkz*2) ^ ((row & 7) << 4))) = (f16)v;
            }
    __syncthreads();

    // ---- layer 3: tok = z2 @ W3^T + b3, K=128, N=256 (two nh passes) ----
    float* outb = out + (size_t)(mt*64)*LE + (size_t)(t+1)*E;
    #pragma unroll
    for (int nh = 0; nh < 2; ++nh) {
        #pragma unroll
        for (int it = 0; it < 8; ++it) {   // stage W3[nh] two kt tiles (32 KB)
            int c = w*8 + it;
            __builtin_amdgcn_global_load_lds(
                (gu32*)((const char*)g_W3s + (size_t)nh*32768 + c*1024 + lane*16),
                (lu32*)(Wb + c*1024 + lane*16), 16, 0, 0);
        }
        __syncthreads();
        #pragma unroll
        for (int m = 0; m < 4; ++m) { acc[m][0] = (f32x4){0,0,0,0}; acc[m][1] = (f32x4){0,0,0,0}; }
        #pragma unroll
        for (int kt = 0; kt < 2; ++kt) {
            #pragma unroll
            for (int kk = 0; kk < 2; ++kk) {
                const int kb0 = kk*64 + kb0_0;
                f16x8 a[4], b[2];
                #pragma unroll
                for (int m = 0; m < 4; ++m) {
                    int ar = m*16 + (lane & 15);
                    a[m] = *(const f16x8*)(Ab + kt*8192 + ar*128 + (kb0 ^ ((ar & 7) << 4)));
                }
                #pragma unroll
                for (int n = 0; n < 2; ++n) {
                    int br = w*32 + n*16 + (lane & 15);
                    b[n] = *(const f16x8*)(Wb + kt*16384 + br*128 + (kb0 ^ ((br & 7) << 4)));
                }
                #pragma unroll
                for (int m = 0; m < 4; ++m)
                    #pragma unroll
                    for (int n = 0; n < 2; ++n)
                        acc[m][n] = __builtin_amdgcn_mfma_f32_16x16x32_f16(a[m], b[n], acc[m][n], 0, 0, 0);
            }
        }
        #pragma unroll
        for (int m = 0; m < 4; ++m)
            #pragma unroll
            for (int n = 0; n < 2; ++n)
                #pragma unroll
                for (int i = 0; i < 4; ++i) {
                    int row = m*16 + ((lane >> 4) << 2) + i;
                    int col = nh*128 + w*32 + n*16 + (lane & 15);
                    outb[(size_t)row*LE + col] = acc[m][n][i] + b3v[nh][n];
                }
        __syncthreads();
    }
}

// ---------------------------------------------------------------------------
extern "C" void kernel_launch(void* const* d_in, const int* in_sizes, int n_in,
                              void* d_out, int out_size, void* d_ws, size_t ws_size,
                              hipStream_t stream) {
    (void)in_sizes; (void)n_in; (void)out_size; (void)d_ws; (void)ws_size;
    const float* hidden = (const float*)d_in[0];
    const float* padded = (const float*)d_in[1];
    const float* W_ih   = (const float*)d_in[2];
    const float* W_hh   = (const float*)d_in[3];
    const float* b_ih   = (const float*)d_in[4];
    const float* b_hh   = (const float*)d_in[5];
    const float* W1     = (const float*)d_in[6];
    const float* b1     = (const float*)d_in[7];
    const float* W2     = (const float*)d_in[8];
    const float* b2     = (const float*)d_in[9];
    const float* W3     = (const float*)d_in[10];
    const float* b3     = (const float*)d_in[11];
    float* out = (float*)d_out;

    conv_w<<<768, 256, 0, stream>>>(W_ih, W_hh, b_ih, b_hh);
    conv_mlp<<<56, 256, 0, stream>>>(W1, W2, W3);
    conv_x<<<16256, 256, 0, stream>>>(padded);
    init_kernel<<<2048, 256, 0, stream>>>(hidden, out);
    for (int t = 0; t < L-1; ++t) {
        gates_mfma<<<dim3(16,16), 512, 0, stream>>>(t);
        mlp_mfma<<<16, 256, 0, stream>>>(
            (t & 1) ^ 1, b1, b2, b3, out, t);
    }
}

// Round 5
// 2166.830 us; speedup vs baseline: 8.4475x; 1.2691x over previous
//
#include <hip/hip_runtime.h>
#include <math.h>
#include <stdint.h>

#define B 1024
#define H 512
#define E 256
#define L 128
#define LE (L*E)   // 32768

typedef _Float16 f16;
typedef _Float16 f16x8 __attribute__((ext_vector_type(8)));
typedef float f32x4 __attribute__((ext_vector_type(4)));
typedef const __attribute__((address_space(1))) uint32_t gu32;
typedef __attribute__((address_space(3))) uint32_t lu32;

// ---------------------------------------------------------------------------
// Persistent state in module device globals (round-1 lesson: d_ws unsafe).
// All buffers fully rewritten every call -> deterministic graph replays.
// ---------------------------------------------------------------------------
__device__ __align__(16) float g_c[B*H];          // fp32 c
// Pre-swizzled fp16 tile images (swizzle baked into GLOBAL layout; ds_read
// applies the same XOR -> conflict-free; global_load_lds stays linear).
__device__ __align__(16) f16 g_Xs[127*16*4*4096]; // X: [t][mt2:16][kt:4] 64x64
__device__ __align__(16) f16 g_Hs[2][16*8*4096];  // H: dbuf [mt2:16][kt:8] 64x64
__device__ __align__(16) f16 g_Ws[16*12*8192];    // gates W' [nt:16][kt:12] 128x64
__device__ __align__(16) f16 g_W1s[8*8192];       // W1' [kt:8] 128x64
__device__ __align__(16) f16 g_W2s[2*8192];       // W2' [kt:2] 128x64
__device__ __align__(16) f16 g_W3s[4*8192];       // W3' [nh:2][kt:2] 128x64
__device__ __align__(16) float g_bsum[2048];      // b_ih+b_hh, n=j*4+g order

__device__ __forceinline__ float sigm(float x) { return 1.0f / (1.0f + expf(-x)); }

// ---------------------------------------------------------------------------
// conv_w: gates W' fp16 tile images (gate-interleaved n=j*4+g) + bias sums
// ---------------------------------------------------------------------------
__global__ __launch_bounds__(256) void conv_w(
    const float* __restrict__ W_ih, const float* __restrict__ W_hh,
    const float* __restrict__ b_ih, const float* __restrict__ b_hh)
{
    int gid = blockIdx.x*256 + threadIdx.x;   // 196608
    int kb  = gid & 7;
    int r1  = gid >> 3;
    int row = r1 & 127;
    int r2  = r1 >> 7;
    int kt  = r2 % 12;
    int nt  = r2 / 12;
    int n = nt*128 + row;
    int g = n & 3, j = n >> 2;
    int wrow = g*512 + j;
    int k = kt*64 + kb*8;
    const float* src = (k < 256) ? (W_ih + wrow*256 + k)
                                 : (W_hh + wrow*512 + (k - 256));
    f16x8 v;
    #pragma unroll
    for (int e = 0; e < 8; ++e) v[e] = (f16)src[e];
    char* dst = (char*)g_Ws + (size_t)(nt*12 + kt)*16384
              + row*128 + ((kb*16) ^ ((row & 7) << 4));
    *(f16x8*)dst = v;
    if (gid < 2048) {
        int gg = gid & 3, jj = gid >> 2;
        g_bsum[gid] = b_ih[gg*512 + jj] + b_hh[gg*512 + jj];
    }
}

// ---------------------------------------------------------------------------
// conv_mlp: W1/W2/W3 fp16 tile images
// ---------------------------------------------------------------------------
__global__ __launch_bounds__(256) void conv_mlp(
    const float* __restrict__ W1, const float* __restrict__ W2,
    const float* __restrict__ W3)
{
    int gid = blockIdx.x*256 + threadIdx.x;   // 14336
    if (gid < 8192) {                         // W1 (128,512) -> 8 tiles
        int s = gid;
        int kb = s & 7, row = (s >> 3) & 127, kt = s >> 10;
        const float* src = W1 + row*512 + kt*64 + kb*8;
        f16x8 v;
        #pragma unroll
        for (int e = 0; e < 8; ++e) v[e] = (f16)src[e];
        char* dst = (char*)g_W1s + (size_t)kt*16384
                  + row*128 + ((kb*16) ^ ((row & 7) << 4));
        *(f16x8*)dst = v;
    } else if (gid < 10240) {                 // W2 (128,128) -> 2 tiles
        int s = gid - 8192;
        int kb = s & 7, row = (s >> 3) & 127, kt = s >> 10;
        const float* src = W2 + row*128 + kt*64 + kb*8;
        f16x8 v;
        #pragma unroll
        for (int e = 0; e < 8; ++e) v[e] = (f16)src[e];
        char* dst = (char*)g_W2s + (size_t)kt*16384
                  + row*128 + ((kb*16) ^ ((row & 7) << 4));
        *(f16x8*)dst = v;
    } else if (gid < 14336) {                 // W3 (256,128) -> [nh:2][kt:2]
        int s = gid - 10240;
        int kb = s & 7, r256 = (s >> 3) & 255, kt = s >> 11;
        int nh = r256 >> 7, row = r256 & 127;
        const float* src = W3 + r256*128 + kt*64 + kb*8;
        f16x8 v;
        #pragma unroll
        for (int e = 0; e < 8; ++e) v[e] = (f16)src[e];
        char* dst = (char*)g_W3s + (size_t)(nh*2 + kt)*16384
                  + row*128 + ((kb*16) ^ ((row & 7) << 4));
        *(f16x8*)dst = v;
    }
}

// ---------------------------------------------------------------------------
// conv_x: X fp16 tile images for all 127 steps
// ---------------------------------------------------------------------------
__global__ __launch_bounds__(256) void conv_x(const float* __restrict__ padded)
{
    int gid = blockIdx.x*256 + threadIdx.x;   // 4161536
    int kb  = gid & 7;
    int r1  = gid >> 3;
    int row = r1 & 63;
    int r2  = r1 >> 6;
    int kt  = r2 & 3;
    int r3  = r2 >> 2;
    int mt  = r3 & 15;
    int t   = r3 >> 4;
    if (t >= 127) return;
    int b = mt*64 + row;
    int k = kt*64 + kb*8;
    const float* src = padded + (size_t)b*LE + t*E + k;
    f16x8 v;
    #pragma unroll
    for (int e = 0; e < 8; ++e) v[e] = (f16)src[e];
    char* dst = (char*)g_Xs + (size_t)((t*16 + mt)*4 + kt)*8192
              + row*128 + ((kb*16) ^ ((row & 7) << 4));
    *(f16x8*)dst = v;
}

// ---------------------------------------------------------------------------
// init: c <- 0, H-image[0] <- hidden, out row 0 <- one-hot
// ---------------------------------------------------------------------------
__global__ __launch_bounds__(256) void init_kernel(
    const float* __restrict__ hidden, float* __restrict__ out)
{
    int i = blockIdx.x * 256 + threadIdx.x;
    if (i < B*H) {
        float hv = hidden[i];
        g_c[i] = 0.0f;
        int b = i >> 9, j = i & 511;
        int mt = b >> 6, row = b & 63, kt = j >> 6, kk = j & 63;
        char* dst = (char*)&g_Hs[0][0] + (size_t)(mt*8 + kt)*8192
                  + row*128 + ((kk*2) ^ ((row & 7) << 4));
        *(f16*)dst = (f16)hv;
    }
    if (i < B*E) {
        int b = i >> 8, e = i & 255;
        out[b*LE + e] = (e == 0) ? 1.0f : 0.0f;
    }
}

// ---------------------------------------------------------------------------
// step_kernel: fused [gates(t) on blocks 0..127] + [mlp(t-1) on blocks 128..143].
// gates: tile 128Mx128N, BK=64, 8 waves (2Mx4N, 4x2 frags), DEPTH-3 staging
//   with counted s_waitcnt vmcnt(8/4/0) + raw s_barrier (no vmcnt(0) drains
//   mid-loop). Epilogue: 4 row-quarters via 17KB Glds, fused LSTM cell update.
// mlp: M=64 rows/block, 8 waves (2Mx4N, 2x2 frags), 3 layers, z1/z2 in LDS
//   as swizzled images; L1 uses depth-2 counted pipeline.
// mlp(t-1) reads g_Hs[t&1] (same buffer gates(t) READS) -> no race.
// ---------------------------------------------------------------------------
__global__ __launch_bounds__(512) void step_kernel(
    int t, const float* __restrict__ b1, const float* __restrict__ b2,
    const float* __restrict__ b3, float* __restrict__ out)
{
    __shared__ __align__(16) char lds[115200];
    const int tid  = threadIdx.x;
    const int lane = tid & 63;
    const int w    = tid >> 6;       // 0..7
    const int wr   = w >> 2;         // 0..1
    const int wc   = w & 3;          // 0..3

    if (blockIdx.x < 128) {
        // =================== gates(t) ===================
        if (t >= 127) return;
        const int mt  = blockIdx.x >> 4;   // 0..7  (128 batch rows)
        const int nt  = blockIdx.x & 15;   // 0..15 (128 gate cols)
        const int cur = t & 1, nxt = cur ^ 1;
        char* ldsA = lds;                   // 3 x 16384
        char* ldsB = lds + 49152;           // 3 x 16384
        float (*Glds)[132] = (float (*)[132])(lds + 98304);  // 16.9 KB

        f32x4 acc[4][2];
        #pragma unroll
        for (int m = 0; m < 4; ++m)
            #pragma unroll
            for (int n = 0; n < 2; ++n) acc[m][n] = (f32x4){0.f,0.f,0.f,0.f};

        auto stage = [&](int kt, int bi) {
            #pragma unroll
            for (int it = 0; it < 2; ++it) {
                int c = w*2 + it;                       // 0..15
                int sub = c >> 3;
                const char* gA = (kt < 4)
                    ? (const char*)g_Xs + (size_t)((t*16 + mt*2 + sub)*4 + kt)*8192
                    : (const char*)&g_Hs[cur][0] + (size_t)((mt*2 + sub)*8 + (kt-4))*8192;
                __builtin_amdgcn_global_load_lds(
                    (gu32*)(gA + (c & 7)*1024 + lane*16),
                    (lu32*)(ldsA + bi*16384 + c*1024 + lane*16), 16, 0, 0);
            }
            const char* gB = (const char*)g_Ws + (size_t)(nt*12 + kt)*16384;
            #pragma unroll
            for (int it = 0; it < 2; ++it) {
                int c = w*2 + it;
                __builtin_amdgcn_global_load_lds(
                    (gu32*)(gB + c*1024 + lane*16),
                    (lu32*)(ldsB + bi*16384 + c*1024 + lane*16), 16, 0, 0);
            }
        };
        stage(0, 0); stage(1, 1); stage(2, 2);

        #pragma unroll
        for (int kt = 0; kt < 12; ++kt) {
            // wait THIS kt's 4 loads (depth-3: up to 8 newer stay in flight)
            if (kt <= 9)       asm volatile("s_waitcnt vmcnt(8)\n\ts_barrier" ::: "memory");
            else if (kt == 10) asm volatile("s_waitcnt vmcnt(4)\n\ts_barrier" ::: "memory");
            else               asm volatile("s_waitcnt vmcnt(0)\n\ts_barrier" ::: "memory");
            const char* Ar = ldsA + (kt % 3)*16384;
            const char* Br = ldsB + (kt % 3)*16384;
            #pragma unroll
            for (int kk = 0; kk < 2; ++kk) {
                const int kb0 = kk*64 + ((lane >> 4) << 4);
                f16x8 a[4], b[2];
                #pragma unroll
                for (int m = 0; m < 4; ++m) {
                    int ar = wr*64 + m*16 + (lane & 15);
                    a[m] = *(const f16x8*)(Ar + ar*128 + (kb0 ^ ((ar & 7) << 4)));
                }
                #pragma unroll
                for (int n = 0; n < 2; ++n) {
                    int br = wc*32 + n*16 + (lane & 15);
                    b[n] = *(const f16x8*)(Br + br*128 + (kb0 ^ ((br & 7) << 4)));
                }
                #pragma unroll
                for (int m = 0; m < 4; ++m)
                    #pragma unroll
                    for (int n = 0; n < 2; ++n)
                        acc[m][n] = __builtin_amdgcn_mfma_f32_16x16x32_f16(
                            a[m], b[n], acc[m][n], 0, 0, 0);
            }
            asm volatile("s_barrier" ::: "memory");   // reads done before restage
            if (kt <= 8) stage(kt + 3, kt % 3);
        }

        // epilogue: 4 quarters of 32 rows through Glds
        #pragma unroll
        for (int q = 0; q < 4; ++q) {
            if (wr == (q >> 1)) {
                #pragma unroll
                for (int lm = 0; lm < 2; ++lm) {
                    int m = (q & 1)*2 + lm;
                    #pragma unroll
                    for (int n = 0; n < 2; ++n)
                        #pragma unroll
                        for (int i = 0; i < 4; ++i) {
                            int rl  = lm*16 + ((lane >> 4) << 2) + i;
                            int col = wc*32 + n*16 + (lane & 15);
                            Glds[rl][col] = acc[m][n][i];
                        }
                }
            }
            __syncthreads();
            #pragma unroll
            for (int s = 0; s < 2; ++s) {
                int cell = tid + s*512;
                int bl = cell >> 5, jl = cell & 31;
                float4 gv = *(const float4*)&Glds[bl][jl*4];
                float4 bs = *(const float4*)&g_bsum[nt*128 + jl*4];
                float iv = sigm(gv.x + bs.x);
                float fv = sigm(gv.y + bs.y);
                float gg = tanhf(gv.z + bs.z);
                float ov = sigm(gv.w + bs.w);
                int bg = mt*128 + q*32 + bl;
                int jg = nt*32 + jl;
                int idx = bg*H + jg;
                float cv = fv * g_c[idx] + iv * gg;
                g_c[idx] = cv;
                float hv = ov * tanhf(cv);
                char* hd = (char*)&g_Hs[nxt][0]
                         + (size_t)((bg >> 6)*8 + (jg >> 6))*8192
                         + (bg & 63)*128 + (((jg & 63)*2) ^ (((bg & 63) & 7) << 4));
                *(f16*)hd = (f16)hv;
            }
            __syncthreads();
        }
    } else {
        // =================== mlp(t-1) ===================
        if (t < 1) return;
        const int tp  = t - 1;
        const int sel = (tp & 1) ^ 1;          // buffer gates(tp) wrote = t&1
        const int mt  = blockIdx.x - 128;      // 0..15, rows [mt*64, +64)
        char* Wb = lds;                         // 2 x 16384
        char* Ab = lds + 32768;                 // 2 x 8192 (later Z2)
        char* Z1 = lds + 49152;                 // 16384
        const char* gH = (const char*)&g_Hs[sel][0] + (size_t)mt*8*8192;
        float* outb = out + (size_t)(mt*64)*LE + (size_t)t*E;  // token tp+1 = t

        float b1v[2], b2v[2], b3v[2][2];
        #pragma unroll
        for (int n = 0; n < 2; ++n) {
            int col = wc*32 + n*16 + (lane & 15);
            b1v[n] = b1[col]; b2v[n] = b2[col];
            b3v[0][n] = b3[col]; b3v[1][n] = b3[128 + col];
        }
        // drain bias loads so counted vmcnt below tracks only staging
        asm volatile("s_waitcnt vmcnt(0)" ::: "memory");

        f32x4 acc[2][2];
        #pragma unroll
        for (int m = 0; m < 2; ++m)
            #pragma unroll
            for (int n = 0; n < 2; ++n) acc[m][n] = (f32x4){0.f,0.f,0.f,0.f};

        auto stage1 = [&](int kt, int bi) {
            __builtin_amdgcn_global_load_lds(
                (gu32*)(gH + (size_t)kt*8192 + w*1024 + lane*16),
                (lu32*)(Ab + bi*8192 + w*1024 + lane*16), 16, 0, 0);
            const char* gW = (const char*)g_W1s + (size_t)kt*16384;
            #pragma unroll
            for (int it = 0; it < 2; ++it) {
                int c = w*2 + it;
                __builtin_amdgcn_global_load_lds(
                    (gu32*)(gW + c*1024 + lane*16),
                    (lu32*)(Wb + bi*16384 + c*1024 + lane*16), 16, 0, 0);
            }
        };
        stage1(0, 0); stage1(1, 1);

        // ---- layer 1: K=512 (8 kt), depth-2 counted pipeline ----
        #pragma unroll
        for (int kt = 0; kt < 8; ++kt) {
            if (kt < 7) asm volatile("s_waitcnt vmcnt(3)\n\ts_barrier" ::: "memory");
            else        asm volatile("s_waitcnt vmcnt(0)\n\ts_barrier" ::: "memory");
            const char* Ar = Ab + (kt & 1)*8192;
            const char* Br = Wb + (kt & 1)*16384;
            #pragma unroll
            for (int kk = 0; kk < 2; ++kk) {
                const int kb0 = kk*64 + ((lane >> 4) << 4);
                f16x8 a[2], b[2];
                #pragma unroll
                for (int m = 0; m < 2; ++m) {
                    int ar = wr*32 + m*16 + (lane & 15);
                    a[m] = *(const f16x8*)(Ar + ar*128 + (kb0 ^ ((ar & 7) << 4)));
                }
                #pragma unroll
                for (int n = 0; n < 2; ++n) {
                    int br = wc*32 + n*16 + (lane & 15);
                    b[n] = *(const f16x8*)(Br + br*128 + (kb0 ^ ((br & 7) << 4)));
                }
                #pragma unroll
                for (int m = 0; m < 2; ++m)
                    #pragma unroll
                    for (int n = 0; n < 2; ++n)
                        acc[m][n] = __builtin_amdgcn_mfma_f32_16x16x32_f16(
                            a[m], b[n], acc[m][n], 0, 0, 0);
            }
            asm volatile("s_barrier" ::: "memory");
            if (kt < 6) stage1(kt + 2, kt & 1);
        }
        // z1 -> relu+bias -> swizzled images in Z1
        #pragma unroll
        for (int m = 0; m < 2; ++m)
            #pragma unroll
            for (int n = 0; n < 2; ++n)
                #pragma unroll
                for (int i = 0; i < 4; ++i) {
                    int row = wr*32 + m*16 + ((lane >> 4) << 2) + i;
                    int col = wc*32 + n*16 + (lane & 15);
                    float v = fmaxf(acc[m][n][i] + b1v[n], 0.0f);
                    *(f16*)(Z1 + (col >> 6)*8192 + row*128
                            + (((col & 63)*2) ^ ((row & 7) << 4))) = (f16)v;
                }
        __syncthreads();

        // ---- layer 2: K=128, W2 staged whole ----
        #pragma unroll
        for (int it = 0; it < 4; ++it) {
            int c = w*4 + it;   // 0..31
            __builtin_amdgcn_global_load_lds(
                (gu32*)((const char*)g_W2s + c*1024 + lane*16),
                (lu32*)(Wb + c*1024 + lane*16), 16, 0, 0);
        }
        asm volatile("s_waitcnt vmcnt(0)\n\ts_barrier" ::: "memory");
        #pragma unroll
        for (int m = 0; m < 2; ++m)
            #pragma unroll
            for (int n = 0; n < 2; ++n) acc[m][n] = (f32x4){0.f,0.f,0.f,0.f};
        #pragma unroll
        for (int kt = 0; kt < 2; ++kt)
            #pragma unroll
            for (int kk = 0; kk < 2; ++kk) {
                const int kb0 = kk*64 + ((lane >> 4) << 4);
                f16x8 a[2], b[2];
                #pragma unroll
                for (int m = 0; m < 2; ++m) {
                    int ar = wr*32 + m*16 + (lane & 15);
                    a[m] = *(const f16x8*)(Z1 + kt*8192 + ar*128 + (kb0 ^ ((ar & 7) << 4)));
                }
                #pragma unroll
                for (int n = 0; n < 2; ++n) {
                    int br = wc*32 + n*16 + (lane & 15);
                    b[n] = *(const f16x8*)(Wb + kt*16384 + br*128 + (kb0 ^ ((br & 7) << 4)));
                }
                #pragma unroll
                for (int m = 0; m < 2; ++m)
                    #pragma unroll
                    for (int n = 0; n < 2; ++n)
                        acc[m][n] = __builtin_amdgcn_mfma_f32_16x16x32_f16(
                            a[m], b[n], acc[m][n], 0, 0, 0);
            }
        // z2 -> relu+bias -> images in Ab (A dbuf dead)
        #pragma unroll
        for (int m = 0; m < 2; ++m)
            #pragma unroll
            for (int n = 0; n < 2; ++n)
                #pragma unroll
                for (int i = 0; i < 4; ++i) {
                    int row = wr*32 + m*16 + ((lane >> 4) << 2) + i;
                    int col = wc*32 + n*16 + (lane & 15);
                    float v = fmaxf(acc[m][n][i] + b2v[n], 0.0f);
                    *(f16*)(Ab + (col >> 6)*8192 + row*128
                            + (((col & 63)*2) ^ ((row & 7) << 4))) = (f16)v;
                }
        __syncthreads();   // also guards Wb overwrite (L2 reads done)

        // ---- layer 3: K=128, N=256 in two nh passes ----
        #pragma unroll
        for (int nh = 0; nh < 2; ++nh) {
            #pragma unroll
            for (int it = 0; it < 4; ++it) {
                int c = w*4 + it;
                __builtin_amdgcn_global_load_lds(
                    (gu32*)((const char*)g_W3s + (size_t)nh*32768 + c*1024 + lane*16),
                    (lu32*)(Wb + c*1024 + lane*16), 16, 0, 0);
            }
            asm volatile("s_waitcnt vmcnt(0)\n\ts_barrier" ::: "memory");
            #pragma unroll
            for (int m = 0; m < 2; ++m)
                #pragma unroll
                for (int n = 0; n < 2; ++n) acc[m][n] = (f32x4){0.f,0.f,0.f,0.f};
            #pragma unroll
            for (int kt = 0; kt < 2; ++kt)
                #pragma unroll
                for (int kk = 0; kk < 2; ++kk) {
                    const int kb0 = kk*64 + ((lane >> 4) << 4);
                    f16x8 a[2], b[2];
                    #pragma unroll
                    for (int m = 0; m < 2; ++m) {
                        int ar = wr*32 + m*16 + (lane & 15);
                        a[m] = *(const f16x8*)(Ab + kt*8192 + ar*128 + (kb0 ^ ((ar & 7) << 4)));
                    }
                    #pragma unroll
                    for (int n = 0; n < 2; ++n) {
                        int br = wc*32 + n*16 + (lane & 15);
                        b[n] = *(const f16x8*)(Wb + kt*16384 + br*128 + (kb0 ^ ((br & 7) << 4)));
                    }
                    #pragma unroll
                    for (int m = 0; m < 2; ++m)
                        #pragma unroll
                        for (int n = 0; n < 2; ++n)
                            acc[m][n] = __builtin_amdgcn_mfma_f32_16x16x32_f16(
                                a[m], b[n], acc[m][n], 0, 0, 0);
                }
            #pragma unroll
            for (int m = 0; m < 2; ++m)
                #pragma unroll
                for (int n = 0; n < 2; ++n)
                    #pragma unroll
                    for (int i = 0; i < 4; ++i) {
                        int row = wr*32 + m*16 + ((lane >> 4) << 2) + i;
                        int col = nh*128 + wc*32 + n*16 + (lane & 15);
                        outb[(size_t)row*LE + col] = acc[m][n][i] + b3v[nh][n];
                    }
            if (nh == 0) asm volatile("s_barrier" ::: "memory");  // Wb reads done
        }
    }
}

// ---------------------------------------------------------------------------
extern "C" void kernel_launch(void* const* d_in, const int* in_sizes, int n_in,
                              void* d_out, int out_size, void* d_ws, size_t ws_size,
                              hipStream_t stream) {
    (void)in_sizes; (void)n_in; (void)out_size; (void)d_ws; (void)ws_size;
    const float* hidden = (const float*)d_in[0];
    const float* padded = (const float*)d_in[1];
    const float* W_ih   = (const float*)d_in[2];
    const float* W_hh   = (const float*)d_in[3];
    const float* b_ih   = (const float*)d_in[4];
    const float* b_hh   = (const float*)d_in[5];
    const float* W1     = (const float*)d_in[6];
    const float* b1     = (const float*)d_in[7];
    const float* W2     = (const float*)d_in[8];
    const float* b2     = (const float*)d_in[9];
    const float* W3     = (const float*)d_in[10];
    const float* b3     = (const float*)d_in[11];
    float* out = (float*)d_out;

    conv_w<<<768, 256, 0, stream>>>(W_ih, W_hh, b_ih, b_hh);
    conv_mlp<<<56, 256, 0, stream>>>(W1, W2, W3);
    conv_x<<<16256, 256, 0, stream>>>(padded);
    init_kernel<<<2048, 256, 0, stream>>>(hidden, out);
    // launch t: gates(t) for t<127, mlp(t-1) for t>=1 -> 128 fused launches
    for (int t = 0; t <= L-1; ++t) {
        step_kernel<<<144, 512, 0, stream>>>(t, b1, b2, b3, out);
    }
}